// Round 8
// baseline (146.326 us; speedup 1.0000x reference)
//
#include <hip/hip_runtime.h>

#define NB 8
#define NC 512
#define NTOK 1024
#define NHEADS 4
#define DKH 128

typedef unsigned short u16;
typedef __attribute__((ext_vector_type(8))) short bf16x8;   // 8 bf16 (4 VGPRs)
typedef __attribute__((ext_vector_type(4))) float f32x4;

__device__ inline u16 f2b(float f) {
    union { float f; unsigned u; } v; v.f = f;
    unsigned r = v.u + 0x7fffu + ((v.u >> 16) & 1u);   // RNE
    return (u16)(r >> 16);
}

// pack two f32 -> bf16 pair (lo=a, hi=b) in 3 VALU ops (add+add+perm), round-half-up
__device__ __forceinline__ unsigned pkbf(float a, float b) {
    union { float f; unsigned u; } va, vb;
    va.f = a; vb.f = b;
    return __builtin_amdgcn_perm(vb.u + 0x8000u, va.u + 0x8000u, 0x07060302u);
}

// async global->LDS DMA, 16B per lane; LDS dest = wave-uniform base + lane*16
__device__ __forceinline__ void gll16(const u16* g, u16* l) {
    __builtin_amdgcn_global_load_lds((const __attribute__((address_space(1))) unsigned*)g,
                                     (__attribute__((address_space(3))) unsigned*)l, 16, 0, 0);
}

// ---- fused prep: 3 transpose+convert jobs in one launch ----
__global__ __launch_bounds__(256) void prep(const float* __restrict__ x, const float* __restrict__ Wp,
                                            const float* __restrict__ Wo,
                                            u16* __restrict__ xsb, u16* __restrict__ WpT, u16* __restrict__ WoT)
{
    __shared__ float tile[32][33];
    const int z = blockIdx.z;
    const float* src; u16* dst; int R, Cc;
    if (z == 0)      { src = Wp; dst = WpT; R = 512; Cc = 1536; }
    else if (z == 1) { if (blockIdx.x >= 16) return; src = Wo; dst = WoT; R = 512; Cc = 512; }
    else             { if (blockIdx.x >= 32) return;
                       src = x + (long)(z-2)*NC*NTOK; dst = xsb + (long)(z-2)*NTOK*NC; R = NC; Cc = NTOK; }
    int c0 = blockIdx.x * 32, r0 = blockIdx.y * 32;
    int tx = threadIdx.x, ty = threadIdx.y;
    #pragma unroll
    for (int k = 0; k < 4; ++k)
        tile[ty + 8*k][tx] = src[(long)(r0 + ty + 8*k) * Cc + c0 + tx];
    __syncthreads();
    #pragma unroll
    for (int k = 0; k < 4; ++k)
        dst[(long)(c0 + ty + 8*k) * R + r0 + tx] = f2b(tile[tx][ty + 8*k]);
}

// ---- QKV projection, m97-style DMA staging, XCD-clustered blocks ----
// id&7 = XCD residue; each XCD owns 8 token-panels x all 12 m-tiles -> B/A L2-resident
// q: [b][h][n][d] PRE-SCALED by scale*log2e; k: 16B-block XOR swizzled; v: transposed+swizzled
__global__ __launch_bounds__(256) void gemm_qkv(const u16* __restrict__ WpT, const u16* __restrict__ xsb,
                                                const float* __restrict__ bp,
                                                u16* __restrict__ qg, u16* __restrict__ kg, u16* __restrict__ vg)
{
    __shared__ union SmU {
        struct { u16 As[128][64]; u16 Bs[128][64]; } s;   // 32 KB, unpadded (DMA-linear, XOR-swizzled cols)
        u16 Os[4][64][72];                                // 36 KB epilogue overlay
    } sm;
    const int tid = threadIdx.x;
    // XCD-cluster decode: 768 blocks; xcd r-r residue; per-XCD: 8 n-panels x 12 m-tiles
    const int id = blockIdx.x;
    const int xcd = id & 7, r = id >> 3;
    const int m0 = (r % 12) * 128;            // qkv column tile
    const int n0 = (xcd * 8 + r / 12) * 128;  // token tile (panel pinned to this XCD)
    const int w = tid >> 6, lane = tid & 63, quad = lane >> 4, lc = lane & 15;
    const int mo = (w & 1) * 64, no = (w >> 1) * 64;
    const int sw8 = (((lane & 7) ^ (lane >> 3)) << 3);   // per-lane swizzled 16B-block col offset
    const int xs = lc & 7;
    const float SL2E = 0.08838834764831845f * 1.4426950408889634f;

    f32x4 acc[4][4] = {};

    for (int k0 = 0; k0 < NC; k0 += 64) {
        __syncthreads();   // all waves done reading previous tile
        #pragma unroll
        for (int p = 0; p < 4; ++p) {
            int row = w*32 + p*8 + (lane >> 3);
            gll16(&WpT[(long)(m0 + row) * NC + k0 + sw8], &sm.s.As[w*32 + p*8][0]);
            gll16(&xsb[(long)(n0 + row) * NC + k0 + sw8], &sm.s.Bs[w*32 + p*8][0]);
        }
        __syncthreads();   // drains vmcnt(0): tile staged
        #pragma unroll
        for (int ks = 0; ks < 2; ++ks) {
            bf16x8 af[4], bfr[4];
            #pragma unroll
            for (int t = 0; t < 4; ++t) {
                af[t]  = *(const bf16x8*)&sm.s.As[mo + t*16 + lc][((ks*4 + quad) ^ xs) << 3];
                bfr[t] = *(const bf16x8*)&sm.s.Bs[no + t*16 + lc][((ks*4 + quad) ^ xs) << 3];
            }
            #pragma unroll
            for (int mt = 0; mt < 4; ++mt)
                #pragma unroll
                for (int nt = 0; nt < 4; ++nt)
                    acc[mt][nt] = __builtin_amdgcn_mfma_f32_16x16x32_bf16(af[mt], bfr[nt], acc[mt][nt], 0, 0, 0);
        }
    }
    __syncthreads();   // protect Os overlay vs other waves' last-tile reads

    // ---- epilogue ----
    const int bb = n0 >> 10;
    const int nblk = n0 & 1023;
    const int cqb = m0 + mo;
    const int h = cqb / 384;
    const int rem = cqb - h * 384;
    const int sel = rem >> 7;             // 0=q 1=k 2=v (wave-uniform)
    const int d_base = rem & 127;
    const float sc = (sel == 0) ? SL2E : 1.0f;   // fold softmax scale into q

    #pragma unroll
    for (int mt = 0; mt < 4; ++mt) {
        int cq0 = cqb + mt*16 + quad*4;
        float b0 = bp[cq0+0]*sc, b1 = bp[cq0+1]*sc, b2 = bp[cq0+2]*sc, b3 = bp[cq0+3]*sc;
        #pragma unroll
        for (int nt = 0; nt < 4; ++nt) {
            f32x4 a = acc[mt][nt];
            int nl = nt*16 + lc;
            int ml = mt*16 + quad*4;
            float v0 = fmaf(a[0], sc, b0), v1 = fmaf(a[1], sc, b1);
            float v2 = fmaf(a[2], sc, b2), v3 = fmaf(a[3], sc, b3);
            if (sel == 2) {
                sm.Os[w][ml+0][nl] = f2b(v0); sm.Os[w][ml+1][nl] = f2b(v1);
                sm.Os[w][ml+2][nl] = f2b(v2); sm.Os[w][ml+3][nl] = f2b(v3);
            } else {
                uint2 pk; pk.x = pkbf(v0, v1); pk.y = pkbf(v2, v3);
                *(uint2*)&sm.Os[w][nl][ml] = pk;
            }
        }
    }
    __builtin_amdgcn_sched_barrier(0);   // pin store->load order (wave-local LDS is in-order)

    const long bhbase = (long)(bb * NHEADS + h);
    const int sw = sw8;
    if (sel == 2) {
        #pragma unroll
        for (int pass = 0; pass < 8; ++pass) {
            int ml  = pass*8 + (lane >> 3);
            int nl0 = (lane & 7) * 8;
            bf16x8 vv = *(const bf16x8*)&sm.Os[w][ml][nl0];
            *(bf16x8*)&vg[((bhbase*DKH + d_base + ml) << 10) + nblk + no + sw] = vv;
        }
    } else if (sel == 1) {
        #pragma unroll
        for (int pass = 0; pass < 8; ++pass) {
            int nl  = pass*8 + (lane >> 3);
            int ml0 = (lane & 7) * 8;
            bf16x8 vv = *(const bf16x8*)&sm.Os[w][nl][ml0];
            *(bf16x8*)&kg[((bhbase*NTOK + nblk + no + nl) << 7) + d_base + sw] = vv;
        }
    } else {
        #pragma unroll
        for (int pass = 0; pass < 8; ++pass) {
            int nl  = pass*8 + (lane >> 3);
            int ml0 = (lane & 7) * 8;
            bf16x8 vv = *(const bf16x8*)&sm.Os[w][nl][ml0];
            *(bf16x8*)&qg[((bhbase*NTOK + nblk + no + nl) << 7) + d_base + ml0] = vv;
        }
    }
}

// ---- flash attention v8: v7 inner loop + LDS-transposed coalesced O write ----
__global__ __launch_bounds__(512) void attn(const u16* __restrict__ qg, const u16* __restrict__ kg,
                                            const u16* __restrict__ vtg, u16* __restrict__ ho)
{
    __shared__ u16 Ks[2][64*128];   // [j][d'] swizzled, unpadded
    __shared__ u16 Vt[2][128*64];   // [d][j'] swizzled, unpadded
    __shared__ u16 Ps[8][16][72];   // per-wave P[i(16)][j(64)]
    __shared__ u16 Ot[8][16][132];  // per-wave O epilogue tile [i(16)][d(128)], pad 4
    const int tid = threadIdx.x;
    const int w = tid >> 6, lane = tid & 63, quad = lane >> 4, lc = lane & 15;
    // XCD-locality decode: id&7 = XCD residue; 4 (b,h) pairs per residue; 8 i-tiles per pair
    const int id = blockIdx.x;
    const int xcd = id & 7, rest = id >> 3, sub = rest & 3, bx = rest >> 2;
    const int pr = xcd + sub*8;
    const int b = pr >> 2, h = pr & 3;
    const int i0 = bx*128 + w*16;
    const long bh = (long)(b * NHEADS + h) << 17;   // *(1024*128)
    const u16* qb = qg + bh;
    const u16* kb = kg + bh;
    const u16* vb = vtg + bh;

    bf16x8 qf[4];
    #pragma unroll
    for (int ks = 0; ks < 4; ++ks)
        qf[ks] = *(const bf16x8*)&qb[(long)(i0 + lc) * DKH + ks*32 + quad*8];

    f32x4 o[8] = {};
    float lsum = 0.f;
    const int xs = lc & 7;

    // stage tile 0 into buffer 0 (8 waves x 2 chunks x 1 KB each for K and V)
    #pragma unroll
    for (int p = 0; p < 2; ++p) {
        int ck = (w*2 + p)*64 + lane;
        gll16(&kb[(long)ck * 8], &Ks[0][(w*2 + p)*512]);
        gll16(&vb[(((long)(ck >> 3)) << 10) + (ck & 7)*8], &Vt[0][(w*2 + p)*512]);
    }

    for (int t = 0; t < 16; ++t) {
        __syncthreads();   // drains vmcnt(0): tile t staged; all waves done with buf[(t-1)&1]
        if (t < 15) {
            long jo = (long)(t+1) * 64;
            #pragma unroll
            for (int p = 0; p < 2; ++p) {
                int ck = (w*2 + p)*64 + lane;
                gll16(&kb[jo*128 + (long)ck*8], &Ks[(t+1)&1][(w*2 + p)*512]);
                gll16(&vb[(((long)(ck >> 3)) << 10) + jo + (ck & 7)*8], &Vt[(t+1)&1][(w*2 + p)*512]);
            }
        }
        const u16* K = Ks[t&1];
        const u16* V = Vt[t&1];

        // S^T = K Q^T: C rows = j, cols = i (lc); logits already in log2 domain (Q pre-scaled)
        f32x4 s[4] = {};
        #pragma unroll
        for (int ks = 0; ks < 4; ++ks)
            #pragma unroll
            for (int jt = 0; jt < 4; ++jt) {
                bf16x8 kf = *(const bf16x8*)&K[(jt*16 + lc)*128 + (((ks*4 + quad) ^ xs) << 3)];
                s[jt] = __builtin_amdgcn_mfma_f32_16x16x32_bf16(kf, qf[ks], s[jt], 0, 0, 0);
            }

        // softmax: no max subtraction (bounded logits), lane-local row sums, perm-packed P
        #pragma unroll
        for (int jt = 0; jt < 4; ++jt) {
            float p0 = __builtin_amdgcn_exp2f(s[jt][0]);
            float p1 = __builtin_amdgcn_exp2f(s[jt][1]);
            float p2 = __builtin_amdgcn_exp2f(s[jt][2]);
            float p3 = __builtin_amdgcn_exp2f(s[jt][3]);
            lsum += (p0 + p1) + (p2 + p3);
            uint2 pk; pk.x = pkbf(p0, p1); pk.y = pkbf(p2, p3);
            *(uint2*)&Ps[w][lc][jt*16 + quad*4] = pk;   // P[i=lc][j-run]
        }
        __builtin_amdgcn_sched_barrier(0);  // wave-private Ps: pin write->read order

        // O^T += V^T P^T
        #pragma unroll
        for (int ks2 = 0; ks2 < 2; ++ks2) {
            bf16x8 pf = *(const bf16x8*)&Ps[w][lc][ks2*32 + quad*8];
            #pragma unroll
            for (int dt = 0; dt < 8; ++dt) {
                bf16x8 vf = *(const bf16x8*)&V[(dt*16 + lc)*64 + (((ks2*4 + quad) ^ xs) << 3)];
                o[dt] = __builtin_amdgcn_mfma_f32_16x16x32_bf16(vf, pf, o[dt], 0, 0, 0);
            }
        }
    }

    // final l reduction across quads (lanes sharing i=lc)
    lsum += __shfl_xor(lsum, 16);
    lsum += __shfl_xor(lsum, 32);
    float inv = 1.0f / lsum;

    // O^T[d][i=lc] -> per-wave LDS tile [i][d] (2-way conflict), then 16B coalesced stores
    #pragma unroll
    for (int dt = 0; dt < 8; ++dt) {
        uint2 pk;
        pk.x = pkbf(o[dt][0] * inv, o[dt][1] * inv);
        pk.y = pkbf(o[dt][2] * inv, o[dt][3] * inv);
        *(uint2*)&Ot[w][lc][dt*16 + quad*4] = pk;
    }
    __builtin_amdgcn_sched_barrier(0);  // wave-private Ot: pin write->read order
    #pragma unroll
    for (int pass = 0; pass < 4; ++pass) {
        int row = pass*4 + (lane >> 4);      // 4 tokens/pass
        int d0  = (lane & 15) * 8;           // 16 lanes x 16B = 256B contiguous per row
        bf16x8 vv = *(const bf16x8*)&Ot[w][row][d0];
        *(bf16x8*)&ho[(long)(b*NTOK + i0 + row) * NC + h*DKH + d0] = vv;
    }
}

// ---- output projection + bias + fp32 residual, XCD-clustered 128m x 64n tiles ----
__global__ __launch_bounds__(256) void gemm_out(const u16* __restrict__ WoT, const u16* __restrict__ ho,
                                                const float* __restrict__ bo, const float* __restrict__ xin,
                                                float* __restrict__ dout)
{
    __shared__ struct { u16 As[128][64]; u16 Bs[64][64]; } sm;   // 24 KB
    const int tid = threadIdx.x;
    // XCD-cluster decode: 512 blocks; per-XCD: 16 n-panels x 4 m-tiles
    const int id = blockIdx.x;
    const int xcd = id & 7, r = id >> 3;
    const int m0 = (r & 3) * 128;             // out-channel tile
    const int n0 = (xcd * 16 + (r >> 2)) * 64; // token tile (panel pinned to this XCD)
    const int w = tid >> 6, lane = tid & 63, quad = lane >> 4, lc = lane & 15;
    const int mo = (w & 1) * 64, no = (w >> 1) * 32;
    const int sw8 = (((lane & 7) ^ (lane >> 3)) << 3);
    const int xs = lc & 7;

    f32x4 acc[4][2] = {};

    for (int k0 = 0; k0 < NC; k0 += 64) {
        __syncthreads();
        #pragma unroll
        for (int p = 0; p < 4; ++p) {
            int row = w*32 + p*8 + (lane >> 3);
            gll16(&WoT[(long)(m0 + row) * NC + k0 + sw8], &sm.As[w*32 + p*8][0]);
        }
        #pragma unroll
        for (int p = 0; p < 2; ++p) {
            int row = w*16 + p*8 + (lane >> 3);
            gll16(&ho[(long)(n0 + row) * NC + k0 + sw8], &sm.Bs[w*16 + p*8][0]);
        }
        __syncthreads();
        #pragma unroll
        for (int ks = 0; ks < 2; ++ks) {
            bf16x8 af[4], bfr[2];
            #pragma unroll
            for (int t = 0; t < 4; ++t)
                af[t] = *(const bf16x8*)&sm.As[mo + t*16 + lc][((ks*4 + quad) ^ xs) << 3];
            #pragma unroll
            for (int t = 0; t < 2; ++t)
                bfr[t] = *(const bf16x8*)&sm.Bs[no + t*16 + lc][((ks*4 + quad) ^ xs) << 3];
            #pragma unroll
            for (int mt = 0; mt < 4; ++mt)
                #pragma unroll
                for (int nt = 0; nt < 2; ++nt)
                    acc[mt][nt] = __builtin_amdgcn_mfma_f32_16x16x32_bf16(af[mt], bfr[nt], acc[mt][nt], 0, 0, 0);
        }
    }

    const int bb = n0 >> 10;
    #pragma unroll
    for (int mt = 0; mt < 4; ++mt) {
        int cc0 = m0 + mo + mt*16 + quad*4;
        float b0 = bo[cc0+0], b1 = bo[cc0+1], b2 = bo[cc0+2], b3 = bo[cc0+3];
        #pragma unroll
        for (int nt = 0; nt < 2; ++nt) {
            int nl = (n0 + no + nt*16 + lc) & (NTOK - 1);
            f32x4 a = acc[mt][nt];
            long ix = ((long)(bb*NC + cc0) << 10) + nl;
            dout[ix]             = a[0] + b0 + xin[ix];
            dout[ix + (1 << 10)] = a[1] + b1 + xin[ix + (1 << 10)];
            dout[ix + (2 << 10)] = a[2] + b2 + xin[ix + (2 << 10)];
            dout[ix + (3 << 10)] = a[3] + b3 + xin[ix + (3 << 10)];
        }
    }
}

extern "C" void kernel_launch(void* const* d_in, const int* in_sizes, int n_in,
                              void* d_out, int out_size, void* d_ws, size_t ws_size,
                              hipStream_t stream)
{
    (void)in_sizes; (void)n_in; (void)out_size; (void)ws_size;
    const float* x  = (const float*)d_in[0];
    const float* Wp = (const float*)d_in[1];
    const float* bp = (const float*)d_in[2];
    const float* Wo = (const float*)d_in[3];
    const float* bo = (const float*)d_in[4];
    float* out = (float*)d_out;

    // workspace layout (u16 elements), total ~42 MiB
    u16* ws  = (u16*)d_ws;
    u16* xsb = ws;                                   // [8192][512] bf16
    u16* WpT = xsb + (long)NB * NTOK * NC;           // [1536][512]
    u16* WoT = WpT + 1536L * 512;                    // [512][512]
    u16* qg  = WoT + 512L * 512;                     // [8][4][1024][128]  (pre-scaled)
    u16* kg  = qg + (long)NB * NHEADS * NTOK * DKH;  // [8][4][1024][128]  (swizzled)
    u16* vtg = kg + (long)NB * NHEADS * NTOK * DKH;  // [8][4][128][1024]  (V transposed, swizzled)
    u16* ho  = vtg + (long)NB * NHEADS * NTOK * DKH; // [8192][512]

    prep<<<dim3(48, 16, 10), dim3(32, 8), 0, stream>>>(x, Wp, Wo, xsb, WpT, WoT);
    gemm_qkv<<<dim3(768), 256, 0, stream>>>(WpT, xsb, bp, qg, kg, vtg);
    attn<<<dim3(256), 512, 0, stream>>>(qg, kg, vtg, ho);
    gemm_out<<<dim3(512), 256, 0, stream>>>(WoT, ho, bo, x, out);
}

// Round 9
// 144.530 us; speedup vs baseline: 1.0124x; 1.0124x over previous
//
#include <hip/hip_runtime.h>

#define NB 8
#define NC 512
#define NTOK 1024
#define NHEADS 4
#define DKH 128

typedef unsigned short u16;
typedef __attribute__((ext_vector_type(8))) short bf16x8;   // 8 bf16 (4 VGPRs)
typedef __attribute__((ext_vector_type(4))) float f32x4;

__device__ inline u16 f2b(float f) {
    union { float f; unsigned u; } v; v.f = f;
    unsigned r = v.u + 0x7fffu + ((v.u >> 16) & 1u);   // RNE
    return (u16)(r >> 16);
}

// pack two f32 -> bf16 pair (lo=a, hi=b) in 3 VALU ops (add+add+perm), round-half-up
__device__ __forceinline__ unsigned pkbf(float a, float b) {
    union { float f; unsigned u; } va, vb;
    va.f = a; vb.f = b;
    return __builtin_amdgcn_perm(vb.u + 0x8000u, va.u + 0x8000u, 0x07060302u);
}

// async global->LDS DMA, 16B per lane; LDS dest = wave-uniform base + lane*16
__device__ __forceinline__ void gll16(const u16* g, u16* l) {
    __builtin_amdgcn_global_load_lds((const __attribute__((address_space(1))) unsigned*)g,
                                     (__attribute__((address_space(3))) unsigned*)l, 16, 0, 0);
}

// ---- fused prep: 3 transpose+convert jobs in one launch ----
__global__ __launch_bounds__(256) void prep(const float* __restrict__ x, const float* __restrict__ Wp,
                                            const float* __restrict__ Wo,
                                            u16* __restrict__ xsb, u16* __restrict__ WpT, u16* __restrict__ WoT)
{
    __shared__ float tile[32][33];
    const int z = blockIdx.z;
    const float* src; u16* dst; int R, Cc;
    if (z == 0)      { src = Wp; dst = WpT; R = 512; Cc = 1536; }
    else if (z == 1) { if (blockIdx.x >= 16) return; src = Wo; dst = WoT; R = 512; Cc = 512; }
    else             { if (blockIdx.x >= 32) return;
                       src = x + (long)(z-2)*NC*NTOK; dst = xsb + (long)(z-2)*NTOK*NC; R = NC; Cc = NTOK; }
    int c0 = blockIdx.x * 32, r0 = blockIdx.y * 32;
    int tx = threadIdx.x, ty = threadIdx.y;
    #pragma unroll
    for (int k = 0; k < 4; ++k)
        tile[ty + 8*k][tx] = src[(long)(r0 + ty + 8*k) * Cc + c0 + tx];
    __syncthreads();
    #pragma unroll
    for (int k = 0; k < 4; ++k)
        dst[(long)(c0 + ty + 8*k) * R + r0 + tx] = f2b(tile[tx][ty + 8*k]);
}

// ---- QKV projection, m97-style DMA staging, XCD-clustered blocks ----
// id&7 = XCD residue; each XCD owns 8 token-panels x all 12 m-tiles -> B/A L2-resident
// q: [b][h][n][d] PRE-SCALED by scale*log2e; k: 16B-block XOR swizzled; v: transposed+swizzled
__global__ __launch_bounds__(256) void gemm_qkv(const u16* __restrict__ WpT, const u16* __restrict__ xsb,
                                                const float* __restrict__ bp,
                                                u16* __restrict__ qg, u16* __restrict__ kg, u16* __restrict__ vg)
{
    __shared__ union SmU {
        struct { u16 As[128][64]; u16 Bs[128][64]; } s;   // 32 KB, unpadded (DMA-linear, XOR-swizzled cols)
        u16 Os[4][64][72];                                // 36 KB epilogue overlay
    } sm;
    const int tid = threadIdx.x;
    // XCD-cluster decode: 768 blocks; xcd r-r residue; per-XCD: 8 n-panels x 12 m-tiles
    const int id = blockIdx.x;
    const int xcd = id & 7, r = id >> 3;
    const int m0 = (r % 12) * 128;            // qkv column tile
    const int n0 = (xcd * 8 + r / 12) * 128;  // token tile (panel pinned to this XCD)
    const int w = tid >> 6, lane = tid & 63, quad = lane >> 4, lc = lane & 15;
    const int mo = (w & 1) * 64, no = (w >> 1) * 64;
    const int sw8 = (((lane & 7) ^ (lane >> 3)) << 3);   // per-lane swizzled 16B-block col offset
    const int xs = lc & 7;
    const float SL2E = 0.08838834764831845f * 1.4426950408889634f;

    f32x4 acc[4][4] = {};

    for (int k0 = 0; k0 < NC; k0 += 64) {
        __syncthreads();   // all waves done reading previous tile
        #pragma unroll
        for (int p = 0; p < 4; ++p) {
            int row = w*32 + p*8 + (lane >> 3);
            gll16(&WpT[(long)(m0 + row) * NC + k0 + sw8], &sm.s.As[w*32 + p*8][0]);
            gll16(&xsb[(long)(n0 + row) * NC + k0 + sw8], &sm.s.Bs[w*32 + p*8][0]);
        }
        __syncthreads();   // drains vmcnt(0): tile staged
        #pragma unroll
        for (int ks = 0; ks < 2; ++ks) {
            bf16x8 af[4], bfr[4];
            #pragma unroll
            for (int t = 0; t < 4; ++t) {
                af[t]  = *(const bf16x8*)&sm.s.As[mo + t*16 + lc][((ks*4 + quad) ^ xs) << 3];
                bfr[t] = *(const bf16x8*)&sm.s.Bs[no + t*16 + lc][((ks*4 + quad) ^ xs) << 3];
            }
            #pragma unroll
            for (int mt = 0; mt < 4; ++mt)
                #pragma unroll
                for (int nt = 0; nt < 4; ++nt)
                    acc[mt][nt] = __builtin_amdgcn_mfma_f32_16x16x32_bf16(af[mt], bfr[nt], acc[mt][nt], 0, 0, 0);
        }
    }
    __syncthreads();   // protect Os overlay vs other waves' last-tile reads

    // ---- epilogue ----
    const int bb = n0 >> 10;
    const int nblk = n0 & 1023;
    const int cqb = m0 + mo;
    const int h = cqb / 384;
    const int rem = cqb - h * 384;
    const int sel = rem >> 7;             // 0=q 1=k 2=v (wave-uniform)
    const int d_base = rem & 127;
    const float sc = (sel == 0) ? SL2E : 1.0f;   // fold softmax scale into q

    #pragma unroll
    for (int mt = 0; mt < 4; ++mt) {
        int cq0 = cqb + mt*16 + quad*4;
        float b0 = bp[cq0+0]*sc, b1 = bp[cq0+1]*sc, b2 = bp[cq0+2]*sc, b3 = bp[cq0+3]*sc;
        #pragma unroll
        for (int nt = 0; nt < 4; ++nt) {
            f32x4 a = acc[mt][nt];
            int nl = nt*16 + lc;
            int ml = mt*16 + quad*4;
            float v0 = fmaf(a[0], sc, b0), v1 = fmaf(a[1], sc, b1);
            float v2 = fmaf(a[2], sc, b2), v3 = fmaf(a[3], sc, b3);
            if (sel == 2) {
                sm.Os[w][ml+0][nl] = f2b(v0); sm.Os[w][ml+1][nl] = f2b(v1);
                sm.Os[w][ml+2][nl] = f2b(v2); sm.Os[w][ml+3][nl] = f2b(v3);
            } else {
                uint2 pk; pk.x = pkbf(v0, v1); pk.y = pkbf(v2, v3);
                *(uint2*)&sm.Os[w][nl][ml] = pk;
            }
        }
    }
    __builtin_amdgcn_sched_barrier(0);   // pin store->load order (wave-local LDS is in-order)

    const long bhbase = (long)(bb * NHEADS + h);
    const int sw = sw8;
    if (sel == 2) {
        #pragma unroll
        for (int pass = 0; pass < 8; ++pass) {
            int ml  = pass*8 + (lane >> 3);
            int nl0 = (lane & 7) * 8;
            bf16x8 vv = *(const bf16x8*)&sm.Os[w][ml][nl0];
            *(bf16x8*)&vg[((bhbase*DKH + d_base + ml) << 10) + nblk + no + sw] = vv;
        }
    } else if (sel == 1) {
        #pragma unroll
        for (int pass = 0; pass < 8; ++pass) {
            int nl  = pass*8 + (lane >> 3);
            int ml0 = (lane & 7) * 8;
            bf16x8 vv = *(const bf16x8*)&sm.Os[w][nl][ml0];
            *(bf16x8*)&kg[((bhbase*NTOK + nblk + no + nl) << 7) + d_base + sw] = vv;
        }
    } else {
        #pragma unroll
        for (int pass = 0; pass < 8; ++pass) {
            int nl  = pass*8 + (lane >> 3);
            int ml0 = (lane & 7) * 8;
            bf16x8 vv = *(const bf16x8*)&sm.Os[w][nl][ml0];
            *(bf16x8*)&qg[((bhbase*NTOK + nblk + no + nl) << 7) + d_base + ml0] = vv;
        }
    }
}

// ---- flash attention v9: 512 blocks x 256 thr (4 waves x 16 q-rows), 2 blocks/CU ----
// v3 topology + XCD clustering + v7 inner loop: co-resident block hides the per-iter
// vmcnt(0)+barrier drain; clustered K/V (4 bh x 512 KB = 2 MB/XCD) stays L2-resident
__global__ __launch_bounds__(256) void attn(const u16* __restrict__ qg, const u16* __restrict__ kg,
                                            const u16* __restrict__ vtg, u16* __restrict__ ho)
{
    __shared__ u16 Ks[2][64*128];   // [j][d'] swizzled, unpadded  (32 KB)
    __shared__ u16 Vt[2][128*64];   // [d][j'] swizzled, unpadded  (32 KB)
    __shared__ u16 Ps[4][16][72];   // per-wave P[i(16)][j(64)]    (9 KB)  -> 73 KB total, 2 blocks/CU
    const int tid = threadIdx.x;
    const int w = tid >> 6, lane = tid & 63, quad = lane >> 4, lc = lane & 15;
    // XCD-locality decode: id&7 = XCD residue; 4 (b,h) pairs per residue; 16 i-tiles per pair
    const int id = blockIdx.x;
    const int xcd = id & 7, rest = id >> 3, sub = rest & 3, bx = rest >> 2;
    const int pr = xcd + sub*8;
    const int b = pr >> 2, h = pr & 3;
    const int i0 = bx*64 + w*16;                    // this wave's 16 q-rows
    const long bh = (long)(b * NHEADS + h) << 17;   // *(1024*128)
    const u16* qb = qg + bh;
    const u16* kb = kg + bh;
    const u16* vb = vtg + bh;

    bf16x8 qf[4];
    #pragma unroll
    for (int ks = 0; ks < 4; ++ks)
        qf[ks] = *(const bf16x8*)&qb[(long)(i0 + lc) * DKH + ks*32 + quad*8];

    f32x4 o[8] = {};
    float lsum = 0.f;
    const int xs = lc & 7;

    // stage tile 0 into buffer 0 (4 waves x 4 chunks x 1 KB each for K and V)
    #pragma unroll
    for (int p = 0; p < 4; ++p) {
        int ck = (w*4 + p)*64 + lane;
        gll16(&kb[(long)ck * 8], &Ks[0][(w*4 + p)*512]);
        gll16(&vb[(((long)(ck >> 3)) << 10) + (ck & 7)*8], &Vt[0][(w*4 + p)*512]);
    }

    for (int t = 0; t < 16; ++t) {
        __syncthreads();   // drains vmcnt(0): tile t staged; all waves done with buf[(t-1)&1]
        if (t < 15) {
            long jo = (long)(t+1) * 64;
            #pragma unroll
            for (int p = 0; p < 4; ++p) {
                int ck = (w*4 + p)*64 + lane;
                gll16(&kb[jo*128 + (long)ck*8], &Ks[(t+1)&1][(w*4 + p)*512]);
                gll16(&vb[(((long)(ck >> 3)) << 10) + jo + (ck & 7)*8], &Vt[(t+1)&1][(w*4 + p)*512]);
            }
        }
        const u16* K = Ks[t&1];
        const u16* V = Vt[t&1];

        // S^T = K Q^T: C rows = j, cols = i (lc); logits already in log2 domain (Q pre-scaled)
        f32x4 s[4] = {};
        #pragma unroll
        for (int ks = 0; ks < 4; ++ks)
            #pragma unroll
            for (int jt = 0; jt < 4; ++jt) {
                bf16x8 kf = *(const bf16x8*)&K[(jt*16 + lc)*128 + (((ks*4 + quad) ^ xs) << 3)];
                s[jt] = __builtin_amdgcn_mfma_f32_16x16x32_bf16(kf, qf[ks], s[jt], 0, 0, 0);
            }

        // softmax: no max subtraction (bounded logits), lane-local row sums, perm-packed P
        #pragma unroll
        for (int jt = 0; jt < 4; ++jt) {
            float p0 = __builtin_amdgcn_exp2f(s[jt][0]);
            float p1 = __builtin_amdgcn_exp2f(s[jt][1]);
            float p2 = __builtin_amdgcn_exp2f(s[jt][2]);
            float p3 = __builtin_amdgcn_exp2f(s[jt][3]);
            lsum += (p0 + p1) + (p2 + p3);
            uint2 pk; pk.x = pkbf(p0, p1); pk.y = pkbf(p2, p3);
            *(uint2*)&Ps[w][lc][jt*16 + quad*4] = pk;   // P[i=lc][j-run]
        }
        __builtin_amdgcn_sched_barrier(0);  // wave-private Ps: pin write->read order

        // O^T += V^T P^T
        #pragma unroll
        for (int ks2 = 0; ks2 < 2; ++ks2) {
            bf16x8 pf = *(const bf16x8*)&Ps[w][lc][ks2*32 + quad*8];
            #pragma unroll
            for (int dt = 0; dt < 8; ++dt) {
                bf16x8 vf = *(const bf16x8*)&V[(dt*16 + lc)*64 + (((ks2*4 + quad) ^ xs) << 3)];
                o[dt] = __builtin_amdgcn_mfma_f32_16x16x32_bf16(vf, pf, o[dt], 0, 0, 0);
            }
        }
    }

    // final l reduction across quads (lanes sharing i=lc)
    lsum += __shfl_xor(lsum, 16);
    lsum += __shfl_xor(lsum, 32);
    float inv = 1.0f / lsum;

    #pragma unroll
    for (int dt = 0; dt < 8; ++dt) {
        uint2 pk;
        pk.x = pkbf(o[dt][0] * inv, o[dt][1] * inv);
        pk.y = pkbf(o[dt][2] * inv, o[dt][3] * inv);
        *(uint2*)&ho[(long)(b*NTOK + i0 + lc) * NC + h*DKH + dt*16 + quad*4] = pk;
    }
}

// ---- output projection + bias + fp32 residual, XCD-clustered 128m x 64n tiles ----
__global__ __launch_bounds__(256) void gemm_out(const u16* __restrict__ WoT, const u16* __restrict__ ho,
                                                const float* __restrict__ bo, const float* __restrict__ xin,
                                                float* __restrict__ dout)
{
    __shared__ struct { u16 As[128][64]; u16 Bs[64][64]; } sm;   // 24 KB
    const int tid = threadIdx.x;
    // XCD-cluster decode: 512 blocks; per-XCD: 16 n-panels x 4 m-tiles
    const int id = blockIdx.x;
    const int xcd = id & 7, r = id >> 3;
    const int m0 = (r & 3) * 128;             // out-channel tile
    const int n0 = (xcd * 16 + (r >> 2)) * 64; // token tile (panel pinned to this XCD)
    const int w = tid >> 6, lane = tid & 63, quad = lane >> 4, lc = lane & 15;
    const int mo = (w & 1) * 64, no = (w >> 1) * 32;
    const int sw8 = (((lane & 7) ^ (lane >> 3)) << 3);
    const int xs = lc & 7;

    f32x4 acc[4][2] = {};

    for (int k0 = 0; k0 < NC; k0 += 64) {
        __syncthreads();
        #pragma unroll
        for (int p = 0; p < 4; ++p) {
            int row = w*32 + p*8 + (lane >> 3);
            gll16(&WoT[(long)(m0 + row) * NC + k0 + sw8], &sm.As[w*32 + p*8][0]);
        }
        #pragma unroll
        for (int p = 0; p < 2; ++p) {
            int row = w*16 + p*8 + (lane >> 3);
            gll16(&ho[(long)(n0 + row) * NC + k0 + sw8], &sm.Bs[w*16 + p*8][0]);
        }
        __syncthreads();
        #pragma unroll
        for (int ks = 0; ks < 2; ++ks) {
            bf16x8 af[4], bfr[2];
            #pragma unroll
            for (int t = 0; t < 4; ++t)
                af[t] = *(const bf16x8*)&sm.As[mo + t*16 + lc][((ks*4 + quad) ^ xs) << 3];
            #pragma unroll
            for (int t = 0; t < 2; ++t)
                bfr[t] = *(const bf16x8*)&sm.Bs[no + t*16 + lc][((ks*4 + quad) ^ xs) << 3];
            #pragma unroll
            for (int mt = 0; mt < 4; ++mt)
                #pragma unroll
                for (int nt = 0; nt < 2; ++nt)
                    acc[mt][nt] = __builtin_amdgcn_mfma_f32_16x16x32_bf16(af[mt], bfr[nt], acc[mt][nt], 0, 0, 0);
        }
    }

    const int bb = n0 >> 10;
    #pragma unroll
    for (int mt = 0; mt < 4; ++mt) {
        int cc0 = m0 + mo + mt*16 + quad*4;
        float b0 = bo[cc0+0], b1 = bo[cc0+1], b2 = bo[cc0+2], b3 = bo[cc0+3];
        #pragma unroll
        for (int nt = 0; nt < 2; ++nt) {
            int nl = (n0 + no + nt*16 + lc) & (NTOK - 1);
            f32x4 a = acc[mt][nt];
            long ix = ((long)(bb*NC + cc0) << 10) + nl;
            dout[ix]             = a[0] + b0 + xin[ix];
            dout[ix + (1 << 10)] = a[1] + b1 + xin[ix + (1 << 10)];
            dout[ix + (2 << 10)] = a[2] + b2 + xin[ix + (2 << 10)];
            dout[ix + (3 << 10)] = a[3] + b3 + xin[ix + (3 << 10)];
        }
    }
}

extern "C" void kernel_launch(void* const* d_in, const int* in_sizes, int n_in,
                              void* d_out, int out_size, void* d_ws, size_t ws_size,
                              hipStream_t stream)
{
    (void)in_sizes; (void)n_in; (void)out_size; (void)ws_size;
    const float* x  = (const float*)d_in[0];
    const float* Wp = (const float*)d_in[1];
    const float* bp = (const float*)d_in[2];
    const float* Wo = (const float*)d_in[3];
    const float* bo = (const float*)d_in[4];
    float* out = (float*)d_out;

    // workspace layout (u16 elements), total ~42 MiB
    u16* ws  = (u16*)d_ws;
    u16* xsb = ws;                                   // [8192][512] bf16
    u16* WpT = xsb + (long)NB * NTOK * NC;           // [1536][512]
    u16* WoT = WpT + 1536L * 512;                    // [512][512]
    u16* qg  = WoT + 512L * 512;                     // [8][4][1024][128]  (pre-scaled)
    u16* kg  = qg + (long)NB * NHEADS * NTOK * DKH;  // [8][4][1024][128]  (swizzled)
    u16* vtg = kg + (long)NB * NHEADS * NTOK * DKH;  // [8][4][128][1024]  (V transposed, swizzled)
    u16* ho  = vtg + (long)NB * NHEADS * NTOK * DKH; // [8192][512]

    prep<<<dim3(48, 16, 10), dim3(32, 8), 0, stream>>>(x, Wp, Wo, xsb, WpT, WoT);
    gemm_qkv<<<dim3(768), 256, 0, stream>>>(WpT, xsb, bp, qg, kg, vtg);
    attn<<<dim3(512), 256, 0, stream>>>(qg, kg, vtg, ho);
    gemm_out<<<dim3(512), 256, 0, stream>>>(WoT, ho, bo, x, out);
}